// Round 1
// baseline (1806.699 us; speedup 1.0000x reference)
//
#include <hip/hip_runtime.h>
#include <math.h>
#include <stdint.h>

#define B_ 2
#define N_ 1024
#define L_ 4096
#define C_ 256
#define H_ 8
#define D_ 32
#define TL 256   // L-tile = one l per thread

// out[m][c] = sum_k in[m][k] * W[k][c] (+ bias[c]); W stored [in,out] row-major
__global__ __launch_bounds__(256)
void proj_kernel(const float* __restrict__ in, const float* __restrict__ W,
                 const float* __restrict__ bias, float* __restrict__ out) {
    __shared__ float row[C_];
    const int m = blockIdx.x;
    const int c = threadIdx.x;
    row[c] = in[(size_t)m * C_ + c];
    __syncthreads();
    float acc = bias ? bias[c] : 0.0f;
    #pragma unroll 8
    for (int k = 0; k < C_; ++k)
        acc = fmaf(row[k], W[(size_t)k * C_ + c], acc);
    out[(size_t)m * C_ + c] = acc;
}

__device__ __forceinline__ float wave_max(float v) {
    #pragma unroll
    for (int off = 32; off >= 1; off >>= 1)
        v = fmaxf(v, __shfl_xor(v, off, 64));
    return v;
}
__device__ __forceinline__ float wave_sum(float v) {
    #pragma unroll
    for (int off = 32; off >= 1; off >>= 1)
        v += __shfl_xor(v, off, 64);
    return v;
}

// One block (256 threads) per (b, n) query row. Thread t owns l = tile*256+t
// in the score/mask phase and output channel c = t in the PV phase.
__global__ __launch_bounds__(256)
void attn_kernel(const float* __restrict__ Q, const float* __restrict__ K,
                 const float* __restrict__ V,
                 const float* __restrict__ Wl1, const float* __restrict__ bl1,
                 const float* __restrict__ Wl2, const float* __restrict__ bl2,
                 float* __restrict__ xpre, float* __restrict__ maskout) {
    const int bn = blockIdx.x;            // 0 .. B*N-1
    const int b = bn / N_;
    const int t = threadIdx.x;            // 0..255
    const int wave = t >> 6;
    const int lane = t & 63;
    const int hc = t >> 5;                // head owning channel t

    __shared__ float q_s[C_];
    __shared__ float p_lds[TL][H_ + 1];   // +1 pad: stride 9 coprime with 32 banks
    __shared__ float red_max[4][H_];
    __shared__ float red_sum[4][H_];
    __shared__ float s_wl1[H_ * H_];
    __shared__ float s_bl1[H_];
    __shared__ float s_wl2[H_];
    __shared__ float s_bl2;

    q_s[t] = Q[(size_t)bn * C_ + t];
    if (t < H_ * H_) s_wl1[t] = Wl1[t];
    if (t < H_) { s_bl1[t] = bl1[t]; s_wl2[t] = Wl2[t]; }
    if (t == 0) s_bl2 = bl2[0];
    __syncthreads();

    const float scale = 0.17677669529663687f;  // 32^-0.5

    float m_run[H_], s_run[H_];
    #pragma unroll
    for (int h = 0; h < H_; ++h) { m_run[h] = -INFINITY; s_run[h] = 0.0f; }
    float x_acc = 0.0f;

    const float* Kb = K + (size_t)b * L_ * C_;
    const float* Vb = V + (size_t)b * L_ * C_;
    float* mrow = maskout + (size_t)bn * L_;

    for (int tile = 0; tile < L_ / TL; ++tile) {
        const int l = tile * TL + t;

        // ---- scores for all 8 heads at (n, l): segmented dot over 256 dims
        float s[H_];
        const float4* kp = reinterpret_cast<const float4*>(Kb + (size_t)l * C_);
        #pragma unroll
        for (int h = 0; h < H_; ++h) {
            float acc = 0.0f;
            #pragma unroll
            for (int d4 = 0; d4 < 8; ++d4) {
                float4 kv = kp[h * 8 + d4];
                const int c0 = h * 32 + d4 * 4;
                acc = fmaf(q_s[c0 + 0], kv.x, acc);
                acc = fmaf(q_s[c0 + 1], kv.y, acc);
                acc = fmaf(q_s[c0 + 2], kv.z, acc);
                acc = fmaf(q_s[c0 + 3], kv.w, acc);
            }
            s[h] = acc * scale;
        }

        // ---- tiny MLP on raw scores -> mask[b,n,l]
        float mk = s_bl2;
        #pragma unroll
        for (int j = 0; j < H_; ++j) {
            float f = s_bl1[j];
            #pragma unroll
            for (int h = 0; h < H_; ++h)
                f = fmaf(s[h], s_wl1[h * H_ + j], f);
            f = fmaxf(f, 0.0f);
            mk = fmaf(f, s_wl2[j], mk);
        }
        mrow[l] = fmaxf(mk, 0.0f);

        // ---- block-wide per-head max
        #pragma unroll
        for (int h = 0; h < H_; ++h) {
            float wm = wave_max(s[h]);
            if (lane == 0) red_max[wave][h] = wm;
        }
        __syncthreads();

        float corr[H_], p[H_], mnew[H_];
        #pragma unroll
        for (int h = 0; h < H_; ++h) {
            float tm = fmaxf(fmaxf(red_max[0][h], red_max[1][h]),
                             fmaxf(red_max[2][h], red_max[3][h]));
            mnew[h] = fmaxf(m_run[h], tm);
            corr[h] = __expf(m_run[h] - mnew[h]);   // 0 on first tile (-inf)
            p[h] = __expf(s[h] - mnew[h]);
            p_lds[t][h] = p[h];
        }

        // ---- block-wide per-head sum of p
        #pragma unroll
        for (int h = 0; h < H_; ++h) {
            float ws = wave_sum(p[h]);
            if (lane == 0) red_sum[wave][h] = ws;
        }
        __syncthreads();

        #pragma unroll
        for (int h = 0; h < H_; ++h) {
            float ts = red_sum[0][h] + red_sum[1][h] + red_sum[2][h] + red_sum[3][h];
            s_run[h] = s_run[h] * corr[h] + ts;
            m_run[h] = mnew[h];
        }

        // corr for this thread's head, static-index select chain (no scratch)
        float corr_c = corr[0];
        #pragma unroll
        for (int h = 1; h < H_; ++h) corr_c = (hc == h) ? corr[h] : corr_c;

        // ---- PV: thread owns channel t; V reads coalesced across threads
        x_acc *= corr_c;
        const float* vp = Vb + (size_t)tile * TL * C_ + t;
        #pragma unroll 8
        for (int l2 = 0; l2 < TL; ++l2)
            x_acc = fmaf(p_lds[l2][hc], vp[(size_t)l2 * C_], x_acc);
        // next tile's first __syncthreads (after red_max writes) protects p_lds
    }

    float s_c = s_run[0];
    #pragma unroll
    for (int h = 1; h < H_; ++h) s_c = (hc == h) ? s_run[h] : s_c;
    xpre[(size_t)bn * C_ + t] = x_acc / s_c;
}

extern "C" void kernel_launch(void* const* d_in, const int* in_sizes, int n_in,
                              void* d_out, int out_size, void* d_ws, size_t ws_size,
                              hipStream_t stream) {
    const float* query = (const float*)d_in[0];
    const float* key   = (const float*)d_in[1];
    const float* value = (const float*)d_in[2];
    // d_in[3] key_padding_mask, d_in[4] hw_lvl: unused by forward
    const float* Wq  = (const float*)d_in[5];
    const float* Wk  = (const float*)d_in[6];
    const float* Wv  = (const float*)d_in[7];
    const float* Wp  = (const float*)d_in[8];
    const float* bp  = (const float*)d_in[9];
    const float* Wl1 = (const float*)d_in[10];
    const float* bl1 = (const float*)d_in[11];
    const float* Wl2 = (const float*)d_in[12];
    const float* bl2 = (const float*)d_in[13];

    float* x_out    = (float*)d_out;                      // [B,N,C] = 524288
    float* mask_out = x_out + (size_t)B_ * N_ * C_;       // [B,N,L,1] = 8388608

    float* ws = (float*)d_ws;
    float* Qp = ws;                                       // B*N*C
    float* Kp = Qp + (size_t)B_ * N_ * C_;                // B*L*C
    float* Vp = Kp + (size_t)B_ * L_ * C_;                // B*L*C
    float* Xp = Vp + (size_t)B_ * L_ * C_;                // B*N*C

    hipLaunchKernelGGL(proj_kernel, dim3(B_ * N_), dim3(C_), 0, stream,
                       query, Wq, (const float*)nullptr, Qp);
    hipLaunchKernelGGL(proj_kernel, dim3(B_ * L_), dim3(C_), 0, stream,
                       key, Wk, (const float*)nullptr, Kp);
    hipLaunchKernelGGL(proj_kernel, dim3(B_ * L_), dim3(C_), 0, stream,
                       value, Wv, (const float*)nullptr, Vp);
    hipLaunchKernelGGL(attn_kernel, dim3(B_ * N_), dim3(256), 0, stream,
                       Qp, Kp, Vp, Wl1, bl1, Wl2, bl2, Xp, mask_out);
    hipLaunchKernelGGL(proj_kernel, dim3(B_ * N_), dim3(C_), 0, stream,
                       Xp, Wp, bp, x_out);
}

// Round 2
// 291.053 us; speedup vs baseline: 6.2075x; 6.2075x over previous
//
#include <hip/hip_runtime.h>
#include <math.h>
#include <stdint.h>

typedef __bf16 bf16;
typedef __bf16 bfx8 __attribute__((ext_vector_type(8)));
typedef short  sh8  __attribute__((ext_vector_type(8)));
typedef float  fx4  __attribute__((ext_vector_type(4)));

#define B_ 2
#define N_ 1024
#define L_ 4096
#define C_ 256
#define H_ 8
#define D_ 32
#define NSPLIT 4
#define LSPAN (L_ / NSPLIT)   // 1024
#define KL 32                 // l per iteration
#define NIT (LSPAN / KL)      // 32
#define SCALE 0.17677669529663687f

// ---------------- projections ----------------
// out[m][c] = sum_k in[m][k] * W[k][c]; W stored [in,out] row-major
__global__ __launch_bounds__(256)
void proj_bf16_kernel(const float* __restrict__ in, const float* __restrict__ W,
                      bf16* __restrict__ out) {
    __shared__ float row[C_];
    const int m = blockIdx.x;
    const int c = threadIdx.x;
    row[c] = in[(size_t)m * C_ + c];
    __syncthreads();
    float acc = 0.0f;
    #pragma unroll 8
    for (int k = 0; k < C_; ++k)
        acc = fmaf(row[k], W[(size_t)k * C_ + c], acc);
    out[(size_t)m * C_ + c] = (bf16)acc;
}

__global__ __launch_bounds__(256)
void proj_f32_kernel(const float* __restrict__ in, const float* __restrict__ W,
                     const float* __restrict__ bias, float* __restrict__ out) {
    __shared__ float row[C_];
    const int m = blockIdx.x;
    const int c = threadIdx.x;
    row[c] = in[(size_t)m * C_ + c];
    __syncthreads();
    float acc = bias[c];
    #pragma unroll 8
    for (int k = 0; k < C_; ++k)
        acc = fmaf(row[k], W[(size_t)k * C_ + c], acc);
    out[(size_t)m * C_ + c] = acc;
}

// ---------------- V transpose: Vp[b][l][32h+d] -> Vt[b][h][d][l] ----------------
__global__ __launch_bounds__(256)
void vtrans_kernel(const bf16* __restrict__ Vp, bf16* __restrict__ Vt) {
    const int o = blockIdx.x * 256 + threadIdx.x;  // 262144 = 2*8*32*512
    const int lc = o & 511;
    const int d  = (o >> 9) & 31;
    const int h  = (o >> 14) & 7;
    const int b  = o >> 17;
    const int l  = lc * 8;
    const bf16* src = Vp + ((size_t)(b * L_ + l) * C_) + h * D_ + d;
    bfx8 v;
    #pragma unroll
    for (int j = 0; j < 8; ++j) v[j] = src[(size_t)j * C_];
    *(bfx8*)(Vt + ((size_t)((b * H_ + h) * D_ + d) * L_ + l)) = v;
}

// ---------------- fused attention ----------------
// grid: 512 blocks = b(2) x ntile(64) x split(4); 8 waves = 8 heads; 16 q-rows.
__global__ __launch_bounds__(512, 4)
void attn_kernel(const bf16* __restrict__ Qb, const bf16* __restrict__ Kb,
                 const bf16* __restrict__ Vt,
                 const float* __restrict__ Wl1, const float* __restrict__ bl1,
                 const float* __restrict__ Wl2, const float* __restrict__ bl2,
                 float* __restrict__ pacc, float* __restrict__ pm,
                 float* __restrict__ ps, float* __restrict__ maskout) {
    const int bx = blockIdx.x;
    const int split = bx & 3;
    const int ntile = (bx >> 2) & 63;
    const int b = bx >> 8;
    const int n0 = ntile * 16;
    const int l0base = split * LSPAN;

    const int tid = threadIdx.x;
    const int h = tid >> 6;           // wave id == head
    const int lane = tid & 63;
    const int r = lane & 15;
    const int g = lane >> 4;

    __shared__ __align__(16) short k_lds[KL * C_];        // 16 KB, XOR-swizzled rows
    __shared__ __align__(16) float s_lds[H_ * 16 * KL];   // 16 KB
    __shared__ __align__(16) float p_lds[H_ * 16 * KL];   // 16 KB
    __shared__ float s_wl1[64], s_bl1[8], s_wl2[8], s_bl2v[1];

    if (tid < 64) s_wl1[tid] = Wl1[tid];
    if (tid < 8) { s_bl1[tid] = bl1[tid]; s_wl2[tid] = Wl2[tid]; }
    if (tid == 0) s_bl2v[0] = bl2[0];

    // persistent Q A-frag: Q[n0+r][32h + 8g .. +7]
    const bfx8 qa = *(const bfx8*)(Qb + ((size_t)(b * N_ + n0 + r) * C_ + h * D_ + g * 8));

    // K staging geometry: 512 threads x 2 chunks of 16B cover 32 rows x 512B
    const int krow = tid >> 5;            // 0..15 (second chunk: +16)
    const int kcolb = (tid & 31) * 16;    // byte offset in row

    // prologue: stage tile 0
    {
        const sh8 k0 = *(const sh8*)(Kb + ((size_t)(b * L_ + l0base + krow) * C_) + kcolb / 2);
        const sh8 k1 = *(const sh8*)(Kb + ((size_t)(b * L_ + l0base + 16 + krow) * C_) + kcolb / 2);
        *(sh8*)((char*)k_lds + ((krow * 512 + kcolb) ^ ((krow & 7) << 4))) = k0;
        *(sh8*)((char*)k_lds + (((krow + 16) * 512 + kcolb) ^ (((krow + 16) & 7) << 4))) = k1;
    }

    float m_run[4], s_run[4];
    fx4 acc0 = {0.f, 0.f, 0.f, 0.f}, acc1 = {0.f, 0.f, 0.f, 0.f};
    #pragma unroll
    for (int i = 0; i < 4; ++i) { m_run[i] = -INFINITY; s_run[i] = 0.f; }

    for (int it = 0; it < NIT; ++it) {
        const int l0 = l0base + it * KL;
        __syncthreads();   // (1) k_lds tile ready; prev-iter s_lds reads done

        // ---- S = Q K^T (2 MFMA) ----
        fx4 s0, s1;
        {
            const int byte0 = ((r) * 512 + h * 64 + g * 16) ^ ((r & 7) << 4);
            const int byte1 = ((r + 16) * 512 + h * 64 + g * 16) ^ (((r + 16) & 7) << 4);
            const bfx8 kb0 = __builtin_bit_cast(bfx8, *(const sh8*)((char*)k_lds + byte0));
            const bfx8 kb1 = __builtin_bit_cast(bfx8, *(const sh8*)((char*)k_lds + byte1));
            const fx4 z = {0.f, 0.f, 0.f, 0.f};
            s0 = __builtin_amdgcn_mfma_f32_16x16x32_bf16(qa, kb0, z, 0, 0, 0);
            s1 = __builtin_amdgcn_mfma_f32_16x16x32_bf16(qa, kb1, z, 0, 0, 0);
        }
        // scale + publish scores for the cross-head mask MLP
        #pragma unroll
        for (int reg = 0; reg < 4; ++reg) {
            s0[reg] *= SCALE; s1[reg] *= SCALE;
            const int n = g * 4 + reg;
            s_lds[(h * 512 + n * 32 + r) ^ ((n & 7) << 2)]        = s0[reg];
            s_lds[(h * 512 + n * 32 + (r + 16)) ^ ((n & 7) << 2)] = s1[reg];
        }
        __syncthreads();   // (2) s_lds ready; k_lds consumed -> restageable

        // ---- issue next K tile loads (hidden under mask/softmax/PV) ----
        sh8 nk0, nk1;
        const bool have_next = (it + 1 < NIT);
        if (have_next) {
            nk0 = *(const sh8*)(Kb + ((size_t)(b * L_ + l0 + KL + krow) * C_) + kcolb / 2);
            nk1 = *(const sh8*)(Kb + ((size_t)(b * L_ + l0 + KL + 16 + krow) * C_) + kcolb / 2);
        }

        // ---- mask MLP: thread covers (n = tid>>5, l = tid&31) ----
        {
            const int mn = tid >> 5;
            const int ml = tid & 31;
            float sv[8];
            #pragma unroll
            for (int hh = 0; hh < 8; ++hh)
                sv[hh] = s_lds[(hh * 512 + mn * 32 + ml) ^ ((mn & 7) << 2)];
            float mk = s_bl2v[0];
            #pragma unroll
            for (int j = 0; j < 8; ++j) {
                float f = s_bl1[j];
                #pragma unroll
                for (int hh = 0; hh < 8; ++hh)
                    f = fmaf(sv[hh], s_wl1[hh * 8 + j], f);
                f = fmaxf(f, 0.f);
                mk = fmaf(f, s_wl2[j], mk);
            }
            maskout[(size_t)(b * N_ + n0 + mn) * L_ + l0 + ml] = fmaxf(mk, 0.f);
        }

        // ---- online softmax (rows n = 4g+reg live in-lane, reg-aligned) ----
        float corr[4];
        #pragma unroll
        for (int reg = 0; reg < 4; ++reg) {
            float mx = fmaxf(s0[reg], s1[reg]);
            mx = fmaxf(mx, __shfl_xor(mx, 1, 64));
            mx = fmaxf(mx, __shfl_xor(mx, 2, 64));
            mx = fmaxf(mx, __shfl_xor(mx, 4, 64));
            mx = fmaxf(mx, __shfl_xor(mx, 8, 64));
            const float mnew = fmaxf(m_run[reg], mx);
            corr[reg] = __expf(m_run[reg] - mnew);
            m_run[reg] = mnew;
            const float p0 = __expf(s0[reg] - mnew);
            const float p1 = __expf(s1[reg] - mnew);
            s0[reg] = p0; s1[reg] = p1;
            float sum = p0 + p1;
            sum += __shfl_xor(sum, 1, 64);
            sum += __shfl_xor(sum, 2, 64);
            sum += __shfl_xor(sum, 4, 64);
            sum += __shfl_xor(sum, 8, 64);
            s_run[reg] = s_run[reg] * corr[reg] + sum;
            acc0[reg] *= corr[reg];
            acc1[reg] *= corr[reg];
        }

        // ---- P -> LDS (wave-private head slice; no block barrier needed) ----
        #pragma unroll
        for (int reg = 0; reg < 4; ++reg) {
            const int n = g * 4 + reg;
            p_lds[(h * 512 + n * 32 + r) ^ ((n & 7) << 2)]        = s0[reg];
            p_lds[(h * 512 + n * 32 + (r + 16)) ^ ((n & 7) << 2)] = s1[reg];
        }
        asm volatile("s_waitcnt lgkmcnt(0)" ::: "memory");
        __builtin_amdgcn_sched_barrier(0);

        // ---- A-frag P (rows r, l = 8g..8g+7) + V^T B-frags + PV MFMA ----
        bfx8 pa;
        {
            const int base = h * 2048 + r * 128 + g * 32;
            const fx4 pf0 = *(const fx4*)((char*)p_lds + ((base)      ^ ((r & 7) << 4)));
            const fx4 pf1 = *(const fx4*)((char*)p_lds + ((base + 16) ^ ((r & 7) << 4)));
            #pragma unroll
            for (int j = 0; j < 4; ++j) { pa[j] = (bf16)pf0[j]; pa[4 + j] = (bf16)pf1[j]; }
        }
        {
            const bfx8 vb0 = *(const bfx8*)(Vt + ((size_t)((b * H_ + h) * D_ + r)      * L_ + l0 + g * 8));
            const bfx8 vb1 = *(const bfx8*)(Vt + ((size_t)((b * H_ + h) * D_ + 16 + r) * L_ + l0 + g * 8));
            acc0 = __builtin_amdgcn_mfma_f32_16x16x32_bf16(pa, vb0, acc0, 0, 0, 0);
            acc1 = __builtin_amdgcn_mfma_f32_16x16x32_bf16(pa, vb1, acc1, 0, 0, 0);
        }

        // ---- write next K tile (reads of current tile finished at barrier 2) ----
        if (have_next) {
            *(sh8*)((char*)k_lds + ((krow * 512 + kcolb) ^ ((krow & 7) << 4))) = nk0;
            *(sh8*)((char*)k_lds + (((krow + 16) * 512 + kcolb) ^ (((krow + 16) & 7) << 4))) = nk1;
        }
    }

    // ---- epilogue: store split partials ----
    const size_t pbase = (size_t)((b * H_ + h) * NSPLIT + split) * N_ + n0;
    #pragma unroll
    for (int reg = 0; reg < 4; ++reg) {
        const int n = g * 4 + reg;
        pacc[(pbase + n) * D_ + r]      = acc0[reg];
        pacc[(pbase + n) * D_ + 16 + r] = acc1[reg];
    }
    if (r == 0) {
        #pragma unroll
        for (int reg = 0; reg < 4; ++reg) {
            pm[pbase + g * 4 + reg] = m_run[reg];
            ps[pbase + g * 4 + reg] = s_run[reg];
        }
    }
}

// ---------------- split-L combine ----------------
__global__ __launch_bounds__(256)
void combine_kernel(const float* __restrict__ pacc, const float* __restrict__ pm,
                    const float* __restrict__ ps, float* __restrict__ xpre) {
    const int idx = blockIdx.x * 256 + threadIdx.x;   // 524288 = 16384 rows x 32 d
    const int d = idx & 31;
    const int row = idx >> 5;
    const int n = row & (N_ - 1);
    const int bh = row >> 10;
    const int b = bh >> 3, h = bh & 7;
    float mv[NSPLIT];
    float M = -INFINITY;
    #pragma unroll
    for (int sp = 0; sp < NSPLIT; ++sp) {
        mv[sp] = pm[(size_t)(bh * NSPLIT + sp) * N_ + n];
        M = fmaxf(M, mv[sp]);
    }
    float S = 0.f, X = 0.f;
    #pragma unroll
    for (int sp = 0; sp < NSPLIT; ++sp) {
        const float w = __expf(mv[sp] - M);
        S = fmaf(ps[(size_t)(bh * NSPLIT + sp) * N_ + n], w, S);
        X = fmaf(pacc[((size_t)(bh * NSPLIT + sp) * N_ + n) * D_ + d], w, X);
    }
    xpre[(size_t)(b * N_ + n) * C_ + h * D_ + d] = X / S;
}

// ---------------- launch ----------------
extern "C" void kernel_launch(void* const* d_in, const int* in_sizes, int n_in,
                              void* d_out, int out_size, void* d_ws, size_t ws_size,
                              hipStream_t stream) {
    const float* query = (const float*)d_in[0];
    const float* key   = (const float*)d_in[1];
    const float* value = (const float*)d_in[2];
    const float* Wq  = (const float*)d_in[5];
    const float* Wk  = (const float*)d_in[6];
    const float* Wv  = (const float*)d_in[7];
    const float* Wp  = (const float*)d_in[8];
    const float* bp  = (const float*)d_in[9];
    const float* Wl1 = (const float*)d_in[10];
    const float* bl1 = (const float*)d_in[11];
    const float* Wl2 = (const float*)d_in[12];
    const float* bl2 = (const float*)d_in[13];

    float* x_out    = (float*)d_out;                      // [B,N,C]
    float* mask_out = x_out + (size_t)B_ * N_ * C_;       // [B,N,L,1]

    const size_t MB = 1048576;
    char* w = (char*)d_ws;
    bf16*  Qb   = (bf16*)w;                       // 1 MB
    bf16*  Kb   = (bf16*)(w + 1 * MB);            // 4 MB
    bf16*  Vt   = (bf16*)(w + 5 * MB);            // 4 MB
    float* pacc = (float*)(w + 9 * MB);           // 8 MB
    float* pm   = (float*)(w + 17 * MB);          // 256 KB
    float* ps   = (float*)(w + 17 * MB + 262144); // 256 KB
    bf16*  Vp   = (bf16*)(w + 9 * MB);            // 4 MB, aliases pacc (dead before attn)
    float* xpre = (float*)(w + 1 * MB);           // 2 MB, aliases Kb (dead after attn)

    hipLaunchKernelGGL(proj_bf16_kernel, dim3(B_ * N_), dim3(C_), 0, stream, query, Wq, Qb);
    hipLaunchKernelGGL(proj_bf16_kernel, dim3(B_ * L_), dim3(C_), 0, stream, key, Wk, Kb);
    hipLaunchKernelGGL(proj_bf16_kernel, dim3(B_ * L_), dim3(C_), 0, stream, value, Wv, Vp);
    hipLaunchKernelGGL(vtrans_kernel, dim3(1024), dim3(256), 0, stream, Vp, Vt);
    hipLaunchKernelGGL(attn_kernel, dim3(B_ * 64 * NSPLIT), dim3(512), 0, stream,
                       Qb, Kb, Vt, Wl1, bl1, Wl2, bl2, pacc, pm, ps, mask_out);
    hipLaunchKernelGGL(combine_kernel, dim3(2048), dim3(256), 0, stream, pacc, pm, ps, xpre);
    hipLaunchKernelGGL(proj_f32_kernel, dim3(B_ * N_), dim3(C_), 0, stream, xpre, Wp, bp, x_out);
}

// Round 4
// 121.763 us; speedup vs baseline: 14.8379x; 2.3903x over previous
//
#include <hip/hip_runtime.h>
#include <math.h>
#include <stdint.h>

typedef __bf16 bf16;
typedef __bf16 bfx8 __attribute__((ext_vector_type(8)));
typedef __bf16 bfx4 __attribute__((ext_vector_type(4)));
typedef short  sh8  __attribute__((ext_vector_type(8)));
typedef float  fx4  __attribute__((ext_vector_type(4)));

#define B_ 2
#define N_ 1024
#define L_ 4096
#define C_ 256
#define H_ 8
#define D_ 32
#define NSPLIT 8
#define LSPAN (L_ / NSPLIT)   // 512
#define KL 32
#define NIT (LSPAN / KL)      // 16
#define SCALE 0.17677669529663687f

// ---------- W transpose to chunked bf16: WT2[k>>3][c][8] ----------
__global__ __launch_bounds__(256)
void wtrans_kernel(const float* __restrict__ Wq, const float* __restrict__ Wk,
                   const float* __restrict__ Wv, const float* __restrict__ Wp,
                   bf16* __restrict__ WTq, bf16* __restrict__ WTk,
                   bf16* __restrict__ WTv, bf16* __restrict__ WTp) {
    const int bid = blockIdx.x;        // 64 = 4 W x 16 tiles
    const int wsel = bid >> 4;
    const int tile = bid & 15;
    const int k0 = (tile >> 2) * 64;
    const int c0 = (tile & 3) * 64;
    const float* W = wsel == 0 ? Wq : wsel == 1 ? Wk : wsel == 2 ? Wv : Wp;
    bf16* WT = wsel == 0 ? WTq : wsel == 1 ? WTk : wsel == 2 ? WTv : WTp;

    __shared__ float t_lds[64][68];    // pad 4 -> rows offset by 272B
    const int tid = threadIdx.x;
    {
        const int r = tid >> 2;
        const int c4 = (tid & 3) * 16;
        const float4* src = (const float4*)(W + (size_t)(k0 + r) * C_ + c0 + c4);
        #pragma unroll
        for (int j = 0; j < 4; ++j)
            *(float4*)&t_lds[r][c4 + 4 * j] = src[j];
    }
    __syncthreads();
    const int c = tid & 63;
    const int gp = tid >> 6;
    #pragma unroll
    for (int i = 0; i < 2; ++i) {
        const int gg = gp + i * 4;     // local k-chunk 0..7
        bfx8 v;
        #pragma unroll
        for (int j = 0; j < 8; ++j) v[j] = (bf16)t_lds[gg * 8 + j][c];
        *(bfx8*)(WT + ((size_t)((k0 >> 3) + gg) * C_ + c0 + c) * 8) = v;
    }
}

// ---------- MFMA projection GEMM: X[f32 M x 256] @ W -> out ----------
// MODE 0: bf16 out (row-major), scaled. MODE 1: bf16 out transposed to Vt. MODE 2: f32 + bias.
template<int MODE>
__device__ __forceinline__
void proj_gemm(const float* __restrict__ X, const bf16* __restrict__ WT2,
               const float* __restrict__ bias, void* __restrict__ outp,
               int m0, float oscale, char* smem) {
    bf16* a2 = (bf16*)smem;            // [4][64][8]  = 4KB
    bf16* b2 = (bf16*)(smem + 4096);   // [4][256][8] = 16KB
    const int tid = threadIdx.x;
    const int w = tid >> 6;
    const int lane = tid & 63;
    const int r = lane & 15;
    const int g = lane >> 4;

    fx4 acc[16];
    #pragma unroll
    for (int t = 0; t < 16; ++t) acc[t] = (fx4){0.f, 0.f, 0.f, 0.f};

    const int am = tid >> 2;
    const int akc = tid & 3;

    for (int kt = 0; kt < 8; ++kt) {
        __syncthreads();
        {   // A stage (f32 -> bf16), coalesced
            const float* src = X + (size_t)(m0 + am) * C_ + kt * 32 + akc * 8;
            float4 x0 = *(const float4*)src;
            float4 x1 = *(const float4*)(src + 4);
            bfx8 v;
            v[0] = (bf16)x0.x; v[1] = (bf16)x0.y; v[2] = (bf16)x0.z; v[3] = (bf16)x0.w;
            v[4] = (bf16)x1.x; v[5] = (bf16)x1.y; v[6] = (bf16)x1.z; v[7] = (bf16)x1.w;
            *(bfx8*)&a2[(akc * 64 + am) * 8] = v;
        }
        #pragma unroll
        for (int gg = 0; gg < 4; ++gg) {   // B stage, coalesced 16B/lane
            bfx8 v = *(const bfx8*)(WT2 + ((size_t)(kt * 4 + gg) * C_ + tid) * 8);
            *(bfx8*)&b2[(gg * 256 + tid) * 8] = v;
        }
        __syncthreads();
        const bfx8 af = *(const bfx8*)&a2[(g * 64 + w * 16 + r) * 8];
        #pragma unroll
        for (int t = 0; t < 16; ++t) {
            const bfx8 bfr = *(const bfx8*)&b2[(g * 256 + t * 16 + r) * 8];
            acc[t] = __builtin_amdgcn_mfma_f32_16x16x32_bf16(af, bfr, acc[t], 0, 0, 0);
        }
    }

    const int mb = m0 + w * 16;
    if (MODE == 0) {
        bf16* out = (bf16*)outp;
        #pragma unroll
        for (int t = 0; t < 16; ++t)
            #pragma unroll
            for (int reg = 0; reg < 4; ++reg)
                out[(size_t)(mb + 4 * g + reg) * C_ + t * 16 + r] = (bf16)(acc[t][reg] * oscale);
    } else if (MODE == 1) {
        bf16* out = (bf16*)outp;   // Vt[b][h][d][l]
        const int bb = m0 >> 12;
        const int l0 = (m0 & (L_ - 1)) + w * 16 + 4 * g;
        #pragma unroll
        for (int t = 0; t < 16; ++t) {
            const int cc = t * 16 + r;
            bfx4 v;
            #pragma unroll
            for (int reg = 0; reg < 4; ++reg) v[reg] = (bf16)acc[t][reg];
            *(bfx4*)(out + ((size_t)((bb * H_ + (cc >> 5)) * D_ + (cc & 31)) * L_ + l0)) = v;
        }
    } else {
        float* out = (float*)outp;
        #pragma unroll
        for (int t = 0; t < 16; ++t) {
            const float bv = bias[t * 16 + r];
            #pragma unroll
            for (int reg = 0; reg < 4; ++reg)
                out[(size_t)(mb + 4 * g + reg) * C_ + t * 16 + r] = acc[t][reg] + bv;
        }
    }
}

__global__ __launch_bounds__(256)
void proj_qkv_kernel(const float* __restrict__ q, const float* __restrict__ k,
                     const float* __restrict__ v,
                     const bf16* __restrict__ WTq, const bf16* __restrict__ WTk,
                     const bf16* __restrict__ WTv,
                     bf16* __restrict__ Qb, bf16* __restrict__ Kb, bf16* __restrict__ Vt) {
    extern __shared__ char smem[];
    const int bid = blockIdx.x;        // 288 = 32 Q + 128 K + 128 V
    if (bid < 32)       proj_gemm<0>(q, WTq, nullptr, Qb, bid * 64, SCALE, smem);
    else if (bid < 160) proj_gemm<0>(k, WTk, nullptr, Kb, (bid - 32) * 64, 1.0f, smem);
    else                proj_gemm<1>(v, WTv, nullptr, Vt, (bid - 160) * 64, 1.0f, smem);
}

__global__ __launch_bounds__(256)
void outproj_kernel(const float* __restrict__ xpre, const bf16* __restrict__ WTp,
                    const float* __restrict__ bp, float* __restrict__ x_out) {
    extern __shared__ char smem[];
    proj_gemm<2>(xpre, WTp, bp, x_out, blockIdx.x * 64, 1.0f, smem);
}

// ---------- fused attention ----------
// grid 1024 = b(2) x ntile(64) x split(8); 8 waves = 8 heads; 16 q-rows.
__global__ __launch_bounds__(512, 8)
void attn_kernel(const bf16* __restrict__ Qb, const bf16* __restrict__ Kb,
                 const bf16* __restrict__ Vt,
                 const float* __restrict__ Wl1, const float* __restrict__ bl1,
                 const float* __restrict__ Wl2, const float* __restrict__ bl2,
                 bf16* __restrict__ pacc, float* __restrict__ pm,
                 float* __restrict__ ps, float* __restrict__ maskout) {
    const int bx = blockIdx.x;
    const int split = bx & (NSPLIT - 1);
    const int ntile = (bx >> 3) & 63;
    const int b = bx >> 9;
    const int n0 = ntile * 16;
    const int l0base = split * LSPAN;

    const int tid = threadIdx.x;
    const int h = tid >> 6;
    const int lane = tid & 63;
    const int r = lane & 15;
    const int g = lane >> 4;

    __shared__ __align__(16) short k_lds[KL * C_];   // 16KB, XOR-swizzled rows
    __shared__ __align__(16) float s_lds[H_ * 512];  // 16KB, 32B-chunk swizzle
    __shared__ __align__(16) float s_wl1[64];
    __shared__ float s_bl1[8], s_wl2[8], s_bl2v[1];

    if (tid < 64) s_wl1[tid] = Wl1[tid];
    if (tid < 8) { s_bl1[tid] = bl1[tid]; s_wl2[tid] = Wl2[tid]; }
    if (tid == 0) s_bl2v[0] = bl2[0];

    // persistent Q A-frag (Q pre-scaled by 1/sqrt(d) at projection)
    const bfx8 qa = *(const bfx8*)(Qb + ((size_t)(b * N_ + n0 + r) * C_ + h * D_ + g * 8));

    const int krow = tid >> 5;
    const int kcolb = (tid & 31) * 16;
    const char* Kbb = (const char*)(Kb + (size_t)b * L_ * C_);

    {   // prologue: stage K tile 0
        sh8 k0v = *(const sh8*)(Kbb + (size_t)(l0base + krow) * 512 + kcolb);
        sh8 k1v = *(const sh8*)(Kbb + (size_t)(l0base + 16 + krow) * 512 + kcolb);
        *(sh8*)((char*)k_lds + ((krow * 512 + kcolb) ^ ((krow & 7) << 4))) = k0v;
        *(sh8*)((char*)k_lds + (((krow + 16) * 512 + kcolb) ^ (((krow + 16) & 7) << 4))) = k1v;
    }

    float m_run = -INFINITY, s_run = 0.f;
    fx4 acc0 = {0.f, 0.f, 0.f, 0.f}, acc1 = {0.f, 0.f, 0.f, 0.f};

    const int mn = tid >> 5;    // mask-MLP coords
    const int ml = tid & 31;
    const int moff = mn * 32 + ((((ml >> 3) ^ (mn >> 2)) & 3) << 3) + (ml & 7);
    const int abase = h * 512 + r * 32 + ((g ^ ((r >> 2) & 3)) << 3);

    for (int it = 0; it < NIT; ++it) {
        const int l0 = l0base + it * KL;
        __syncthreads();   // (1) k_lds ready; prev s_lds reads done

        // ---- S = Q K^T ----
        fx4 s0, s1;
        {
            const int byte0 = (r * 512 + h * 64 + g * 16) ^ ((r & 7) << 4);
            const int byte1 = ((r + 16) * 512 + h * 64 + g * 16) ^ (((r + 16) & 7) << 4);
            const bfx8 kb0 = __builtin_bit_cast(bfx8, *(const sh8*)((char*)k_lds + byte0));
            const bfx8 kb1 = __builtin_bit_cast(bfx8, *(const sh8*)((char*)k_lds + byte1));
            const fx4 z = {0.f, 0.f, 0.f, 0.f};
            s0 = __builtin_amdgcn_mfma_f32_16x16x32_bf16(qa, kb0, z, 0, 0, 0);
            s1 = __builtin_amdgcn_mfma_f32_16x16x32_bf16(qa, kb1, z, 0, 0, 0);
        }
        // publish S (D-layout rows n=4g+reg, cols r / r+16), 32B-chunk swizzle
        #pragma unroll
        for (int reg = 0; reg < 4; ++reg) {
            const int base = h * 512 + (4 * g + reg) * 32;
            s_lds[base + ((((r >> 3)    ) ^ g) << 3) + (r & 7)] = s0[reg];
            s_lds[base + ((((r >> 3) + 2) ^ g) << 3) + (r & 7)] = s1[reg];
        }
        __syncthreads();   // (2) s_lds ready; k_lds consumed

        // ---- stage next K tile into regs; V loads for this iter ----
        sh8 nk0, nk1;
        const bool have_next = (it + 1 < NIT);
        if (have_next) {
            nk0 = *(const sh8*)(Kbb + (size_t)(l0 + KL + krow) * 512 + kcolb);
            nk1 = *(const sh8*)(Kbb + (size_t)(l0 + KL + 16 + krow) * 512 + kcolb);
        }
        const bfx8 vb0 = *(const bfx8*)(Vt + ((size_t)((b * H_ + h) * D_ + r)      * L_ + l0 + g * 8));
        const bfx8 vb1 = *(const bfx8*)(Vt + ((size_t)((b * H_ + h) * D_ + 16 + r) * L_ + l0 + g * 8));

        // ---- mask MLP (all 512 threads; weights broadcast from LDS) ----
        {
            float sv[8];
            #pragma unroll
            for (int hh = 0; hh < 8; ++hh) sv[hh] = s_lds[hh * 512 + moff];
            float f0 = s_bl1[0], f1 = s_bl1[1], f2 = s_bl1[2], f3 = s_bl1[3];
            float f4 = s_bl1[4], f5 = s_bl1[5], f6 = s_bl1[6], f7 = s_bl1[7];
            #pragma unroll
            for (int hh = 0; hh < 8; ++hh) {
                const float svh = sv[hh];
                const fx4 w0 = *(const fx4*)&s_wl1[hh * 8];
                const fx4 w1 = *(const fx4*)&s_wl1[hh * 8 + 4];
                f0 = fmaf(svh, w0[0], f0); f1 = fmaf(svh, w0[1], f1);
                f2 = fmaf(svh, w0[2], f2); f3 = fmaf(svh, w0[3], f3);
                f4 = fmaf(svh, w1[0], f4); f5 = fmaf(svh, w1[1], f5);
                f6 = fmaf(svh, w1[2], f6); f7 = fmaf(svh, w1[3], f7);
            }
            float mk = s_bl2v[0];
            mk = fmaf(fmaxf(f0, 0.f), s_wl2[0], mk);
            mk = fmaf(fmaxf(f1, 0.f), s_wl2[1], mk);
            mk = fmaf(fmaxf(f2, 0.f), s_wl2[2], mk);
            mk = fmaf(fmaxf(f3, 0.f), s_wl2[3], mk);
            mk = fmaf(fmaxf(f4, 0.f), s_wl2[4], mk);
            mk = fmaf(fmaxf(f5, 0.f), s_wl2[5], mk);
            mk = fmaf(fmaxf(f6, 0.f), s_wl2[6], mk);
            mk = fmaf(fmaxf(f7, 0.f), s_wl2[7], mk);
            maskout[(size_t)(b * N_ + n0 + mn) * L_ + l0 + ml] = fmaxf(mk, 0.f);
        }

        // ---- A-layout S readback: row r, l = 8g..8g+7 ----
        const fx4 sa0 = *(const fx4*)&s_lds[abase];
        const fx4 sa1 = *(const fx4*)&s_lds[abase + 4];

        // ---- online softmax, defer-max (THR=8) ----
        float tmax = fmaxf(fmaxf(fmaxf(sa0[0], sa0[1]), fmaxf(sa0[2], sa0[3])),
                           fmaxf(fmaxf(sa1[0], sa1[1]), fmaxf(sa1[2], sa1[3])));
        tmax = fmaxf(tmax, __shfl_xor(tmax, 16, 64));
        tmax = fmaxf(tmax, __shfl_xor(tmax, 32, 64));
        if (!__all(tmax <= m_run + 8.0f)) {   // wave-uniform slow path (no barrier inside)
            const float mnew = fmaxf(m_run, tmax);
            const float corr = __expf(m_run - mnew);
            m_run = mnew;
            s_run *= corr;
            #pragma unroll
            for (int reg = 0; reg < 4; ++reg) {
                const float cd = __shfl(corr, 4 * g + reg, 64);
                acc0[reg] *= cd; acc1[reg] *= cd;
            }
        }
        float p0 = __expf(sa0[0] - m_run), p1 = __expf(sa0[1] - m_run);
        float p2 = __expf(sa0[2] - m_run), p3 = __expf(sa0[3] - m_run);
        float p4 = __expf(sa1[0] - m_run), p5 = __expf(sa1[1] - m_run);
        float p6 = __expf(sa1[2] - m_run), p7 = __expf(sa1[3] - m_run);
        float psum = ((p0 + p1) + (p2 + p3)) + ((p4 + p5) + (p6 + p7));
        psum += __shfl_xor(psum, 16, 64);
        psum += __shfl_xor(psum, 32, 64);
        s_run += psum;

        bfx8 pa;
        pa[0] = (bf16)p0; pa[1] = (bf16)p1; pa[2] = (bf16)p2; pa[3] = (bf16)p3;
        pa[4] = (bf16)p4; pa[5] = (bf16)p5; pa[6] = (bf16)p6; pa[7] = (bf16)p7;

        acc0 = __builtin_amdgcn_mfma_f32_16x16x32_bf16(pa, vb0, acc0, 0, 0, 0);
        acc1 = __builtin_amdgcn_mfma_f32_16x16x32_bf16(pa, vb1, acc1, 0, 0, 0);

        if (have_next) {   // write next K tile (reads finished at barrier 2)
            *(sh8*)((char*)k_lds + ((krow * 512 + kcolb) ^ ((krow & 7) << 4))) = nk0;
            *(sh8*)((char*)k_lds + (((krow + 16) * 512 + kcolb) ^ (((krow + 16) & 7) << 4))) = nk1;
        }
    }

    // ---- epilogue: split partials ----
    const size_t pbase = (size_t)((b * H_ + h) * NSPLIT + split) * N_ + n0;
    #pragma unroll
    for (int reg = 0; reg < 4; ++reg) {
        const int n = 4 * g + reg;
        pacc[(pbase + n) * D_ + r]      = (bf16)acc0[reg];
        pacc[(pbase + n) * D_ + 16 + r] = (bf16)acc1[reg];
    }
    if (lane < 16) {
        pm[pbase + lane] = m_run;
        ps[pbase + lane] = s_run;
    }
}

// ---------- split-L combine ----------
__global__ __launch_bounds__(256)
void combine_kernel(const bf16* __restrict__ pacc, const float* __restrict__ pm,
                    const float* __restrict__ ps, float* __restrict__ xpre) {
    const int idx = blockIdx.x * 256 + threadIdx.x;   // 524288
    const int d = idx & 31;
    const int row = idx >> 5;
    const int n = row & (N_ - 1);
    const int bh = row >> 10;
    const int b = bh >> 3, hh = bh & 7;
    float mv[NSPLIT];
    float M = -INFINITY;
    #pragma unroll
    for (int sp = 0; sp < NSPLIT; ++sp) {
        mv[sp] = pm[(size_t)(bh * NSPLIT + sp) * N_ + n];
        M = fmaxf(M, mv[sp]);
    }
    float S = 0.f, X = 0.f;
    #pragma unroll
    for (int sp = 0; sp < NSPLIT; ++sp) {
        const float w = __expf(mv[sp] - M);
        S = fmaf(ps[(size_t)(bh * NSPLIT + sp) * N_ + n], w, S);
        X = fmaf((float)pacc[((size_t)(bh * NSPLIT + sp) * N_ + n) * D_ + d], w, X);
    }
    xpre[(size_t)(b * N_ + n) * C_ + hh * D_ + d] = X / S;
}

// ---------- launch ----------
extern "C" void kernel_launch(void* const* d_in, const int* in_sizes, int n_in,
                              void* d_out, int out_size, void* d_ws, size_t ws_size,
                              hipStream_t stream) {
    const float* query = (const float*)d_in[0];
    const float* key   = (const float*)d_in[1];
    const float* value = (const float*)d_in[2];
    const float* Wq  = (const float*)d_in[5];
    const float* Wk  = (const float*)d_in[6];
    const float* Wv  = (const float*)d_in[7];
    const float* Wp  = (const float*)d_in[8];
    const float* bp  = (const float*)d_in[9];
    const float* Wl1 = (const float*)d_in[10];
    const float* bl1 = (const float*)d_in[11];
    const float* Wl2 = (const float*)d_in[12];
    const float* bl2 = (const float*)d_in[13];

    float* x_out    = (float*)d_out;                 // [B,N,C]
    float* mask_out = x_out + (size_t)B_ * N_ * C_;  // [B,N,L,1]

    char* w = (char*)d_ws;
    bf16*  WTq  = (bf16*)(w);
    bf16*  WTk  = (bf16*)(w + (128 << 10));
    bf16*  WTv  = (bf16*)(w + (256 << 10));
    bf16*  WTp  = (bf16*)(w + (384 << 10));
    bf16*  Qb   = (bf16*)(w + (512 << 10));          // 1MB
    bf16*  Kb   = (bf16*)(w + (1536 << 10));         // 4MB
    bf16*  Vt   = (bf16*)(w + (5632 << 10));         // 4MB
    bf16*  pacc = (bf16*)(w + (9728 << 10));         // 8MB
    float* pm   = (float*)(w + (17920 << 10));       // 512KB
    float* ps   = (float*)(w + (18432 << 10));       // 512KB
    float* xpre = (float*)(w + (512 << 10));         // 2MB, aliases Qb+Kb[0:1MB] (dead post-attn)

    hipLaunchKernelGGL(wtrans_kernel, dim3(64), dim3(256), 0, stream,
                       Wq, Wk, Wv, Wp, WTq, WTk, WTv, WTp);
    hipLaunchKernelGGL(proj_qkv_kernel, dim3(288), dim3(256), 20480, stream,
                       query, key, value, WTq, WTk, WTv, Qb, Kb, Vt);
    hipLaunchKernelGGL(attn_kernel, dim3(1024), dim3(512), 0, stream,
                       Qb, Kb, Vt, Wl1, bl1, Wl2, bl2, pacc, pm, ps, mask_out);
    hipLaunchKernelGGL(combine_kernel, dim3(2048), dim3(256), 0, stream, pacc, pm, ps, xpre);
    hipLaunchKernelGGL(outproj_kernel, dim3(32), dim3(256), 20480, stream, xpre, WTp, bp, x_out);
}

// Round 5
// 87.460 us; speedup vs baseline: 20.6574x; 1.3922x over previous
//
#include <hip/hip_runtime.h>
#include <math.h>
#include <stdint.h>

typedef __bf16 bf16;
typedef __bf16 bfx8 __attribute__((ext_vector_type(8)));
typedef __bf16 bfx4 __attribute__((ext_vector_type(4)));
typedef short  sh8  __attribute__((ext_vector_type(8)));
typedef float  fx4  __attribute__((ext_vector_type(4)));

#define B_ 2
#define N_ 1024
#define L_ 4096
#define C_ 256
#define H_ 8
#define D_ 32
#define NSPLIT 8
#define LSPAN (L_ / NSPLIT)   // 512
#define KL 32
#define NIT (LSPAN / KL)      // 16
#define SCALE 0.17677669529663687f

// ---------- W transpose to chunked bf16: WT2[k>>3][c][8] ----------
__global__ __launch_bounds__(256)
void wtrans_kernel(const float* __restrict__ Wq, const float* __restrict__ Wk,
                   const float* __restrict__ Wv, const float* __restrict__ Wp,
                   bf16* __restrict__ WTq, bf16* __restrict__ WTk,
                   bf16* __restrict__ WTv, bf16* __restrict__ WTp) {
    const int bid = blockIdx.x;        // 64 = 4 W x 16 tiles
    const int wsel = bid >> 4;
    const int tile = bid & 15;
    const int k0 = (tile >> 2) * 64;
    const int c0 = (tile & 3) * 64;
    const float* W = wsel == 0 ? Wq : wsel == 1 ? Wk : wsel == 2 ? Wv : Wp;
    bf16* WT = wsel == 0 ? WTq : wsel == 1 ? WTk : wsel == 2 ? WTv : WTp;

    __shared__ float t_lds[64][68];
    const int tid = threadIdx.x;
    {
        const int r = tid >> 2;
        const int c4 = (tid & 3) * 16;
        const float4* src = (const float4*)(W + (size_t)(k0 + r) * C_ + c0 + c4);
        #pragma unroll
        for (int j = 0; j < 4; ++j)
            *(float4*)&t_lds[r][c4 + 4 * j] = src[j];
    }
    __syncthreads();
    const int c = tid & 63;
    const int gp = tid >> 6;
    #pragma unroll
    for (int i = 0; i < 2; ++i) {
        const int gg = gp + i * 4;
        bfx8 v;
        #pragma unroll
        for (int j = 0; j < 8; ++j) v[j] = (bf16)t_lds[gg * 8 + j][c];
        *(bfx8*)(WT + ((size_t)((k0 >> 3) + gg) * C_ + c0 + c) * 8) = v;
    }
}

// ---------- MFMA projection GEMM: BM=64 x BN=64 tile ----------
// MODE 0: bf16 out, scaled. MODE 1: bf16 out transposed to Vt. MODE 2: f32 + bias.
template<int MODE>
__device__ __forceinline__
void proj_gemm(const float* __restrict__ X, const bf16* __restrict__ WT2,
               const float* __restrict__ bias, void* __restrict__ outp,
               int m0, int n0, float oscale, char* smem) {
    bf16* a2 = (bf16*)smem;            // [4 kc][64 m][8]  = 4KB
    bf16* b2 = (bf16*)(smem + 4096);   // [4 kc][64 c][8]  = 4KB
    const int tid = threadIdx.x;
    const int w = tid >> 6;
    const int lane = tid & 63;
    const int r = lane & 15;
    const int g = lane >> 4;

    fx4 acc[4];
    #pragma unroll
    for (int t = 0; t < 4; ++t) acc[t] = (fx4){0.f, 0.f, 0.f, 0.f};

    const int am = tid >> 2;
    const int akc = tid & 3;
    const int bgg = tid >> 6;
    const int bc  = tid & 63;

    for (int kt = 0; kt < 8; ++kt) {
        __syncthreads();
        {   // A stage (f32 -> bf16), coalesced
            const float* src = X + (size_t)(m0 + am) * C_ + kt * 32 + akc * 8;
            float4 x0 = *(const float4*)src;
            float4 x1 = *(const float4*)(src + 4);
            bfx8 v;
            v[0] = (bf16)x0.x; v[1] = (bf16)x0.y; v[2] = (bf16)x0.z; v[3] = (bf16)x0.w;
            v[4] = (bf16)x1.x; v[5] = (bf16)x1.y; v[6] = (bf16)x1.z; v[7] = (bf16)x1.w;
            *(bfx8*)&a2[(akc * 64 + am) * 8] = v;
        }
        {   // B stage, 16B/lane
            bfx8 v = *(const bfx8*)(WT2 + ((size_t)(kt * 4 + bgg) * C_ + n0 + bc) * 8);
            *(bfx8*)&b2[(bgg * 64 + bc) * 8] = v;
        }
        __syncthreads();
        const bfx8 af = *(const bfx8*)&a2[(g * 64 + w * 16 + r) * 8];
        #pragma unroll
        for (int t = 0; t < 4; ++t) {
            const bfx8 bfr = *(const bfx8*)&b2[(g * 64 + t * 16 + r) * 8];
            acc[t] = __builtin_amdgcn_mfma_f32_16x16x32_bf16(af, bfr, acc[t], 0, 0, 0);
        }
    }

    const int mb = m0 + w * 16;
    if (MODE == 0) {
        bf16* out = (bf16*)outp;
        #pragma unroll
        for (int t = 0; t < 4; ++t)
            #pragma unroll
            for (int reg = 0; reg < 4; ++reg)
                out[(size_t)(mb + 4 * g + reg) * C_ + n0 + t * 16 + r] = (bf16)(acc[t][reg] * oscale);
    } else if (MODE == 1) {
        bf16* out = (bf16*)outp;   // Vt[b][h][d][l]
        const int bb = m0 >> 12;
        const int l0 = (m0 & (L_ - 1)) + w * 16 + 4 * g;
        #pragma unroll
        for (int t = 0; t < 4; ++t) {
            const int cc = n0 + t * 16 + r;
            bfx4 v;
            #pragma unroll
            for (int reg = 0; reg < 4; ++reg) v[reg] = (bf16)acc[t][reg];
            *(bfx4*)(out + ((size_t)((bb * H_ + (cc >> 5)) * D_ + (cc & 31)) * L_ + l0)) = v;
        }
    } else {
        float* out = (float*)outp;
        #pragma unroll
        for (int t = 0; t < 4; ++t) {
            const float bv = bias[n0 + t * 16 + r];
            #pragma unroll
            for (int reg = 0; reg < 4; ++reg)
                out[(size_t)(mb + 4 * g + reg) * C_ + n0 + t * 16 + r] = acc[t][reg] + bv;
        }
    }
}

__global__ __launch_bounds__(256)
void proj_qkv_kernel(const float* __restrict__ q, const float* __restrict__ k,
                     const float* __restrict__ v,
                     const bf16* __restrict__ WTq, const bf16* __restrict__ WTk,
                     const bf16* __restrict__ WTv,
                     bf16* __restrict__ Qb, bf16* __restrict__ Kb, bf16* __restrict__ Vt) {
    extern __shared__ char smem[];
    const int bid = blockIdx.x;        // 1152 = 128 Q + 512 K + 512 V
    if (bid < 128) {
        proj_gemm<0>(q, WTq, nullptr, Qb, (bid >> 2) * 64, (bid & 3) * 64, SCALE, smem);
    } else if (bid < 640) {
        const int i = bid - 128;
        proj_gemm<0>(k, WTk, nullptr, Kb, (i >> 2) * 64, (i & 3) * 64, 1.0f, smem);
    } else {
        const int i = bid - 640;
        proj_gemm<1>(v, WTv, nullptr, Vt, (i >> 2) * 64, (i & 3) * 64, 1.0f, smem);
    }
}

__global__ __launch_bounds__(256)
void outproj_kernel(const float* __restrict__ xpre, const bf16* __restrict__ WTp,
                    const float* __restrict__ bp, float* __restrict__ x_out) {
    extern __shared__ char smem[];
    proj_gemm<2>(xpre, WTp, bp, x_out, (blockIdx.x >> 2) * 64, (blockIdx.x & 3) * 64, 1.0f, smem);
}

// ---------- fused mask MLP for two score vectors (weights via SGPR s_loads) ----------
__device__ __forceinline__
void mask_mlp2(const float sv0[8], const float sv1[8],
               const float* __restrict__ Wl1, const float* __restrict__ bl1,
               const float* __restrict__ Wl2, const float bl2v,
               float* mk0, float* mk1) {
    float f0[8], f1[8];
    #pragma unroll
    for (int j = 0; j < 8; ++j) { const float b = bl1[j]; f0[j] = b; f1[j] = b; }
    #pragma unroll
    for (int hh = 0; hh < 8; ++hh) {
        #pragma unroll
        for (int j = 0; j < 8; ++j) {
            const float w = Wl1[hh * 8 + j];     // uniform addr -> s_load (SGPR)
            f0[j] = fmaf(sv0[hh], w, f0[j]);
            f1[j] = fmaf(sv1[hh], w, f1[j]);
        }
    }
    float m0 = bl2v, m1 = bl2v;
    #pragma unroll
    for (int j = 0; j < 8; ++j) {
        const float w = Wl2[j];
        m0 = fmaf(fmaxf(f0[j], 0.f), w, m0);
        m1 = fmaf(fmaxf(f1[j], 0.f), w, m1);
    }
    *mk0 = fmaxf(m0, 0.f);
    *mk1 = fmaxf(m1, 0.f);
}

// ---------- fused attention ----------
// grid 512 = b(2) x ntile(32 of 32 rows) x split(8); 8 waves = 8 heads; 2 sub-tiles.
__global__ __launch_bounds__(512, 4)
void attn_kernel(const bf16* __restrict__ Qb, const bf16* __restrict__ Kb,
                 const bf16* __restrict__ Vt,
                 const float* __restrict__ Wl1, const float* __restrict__ bl1,
                 const float* __restrict__ Wl2, const float* __restrict__ bl2,
                 bf16* __restrict__ pacc, float* __restrict__ pm,
                 float* __restrict__ ps, float* __restrict__ maskout) {
    const int bx = blockIdx.x;
    const int split = bx & (NSPLIT - 1);
    const int nt = (bx >> 3) & 31;
    const int b = bx >> 8;
    const int n0 = nt * 32;
    const int l0base = split * LSPAN;

    const int tid = threadIdx.x;
    const int h = tid >> 6;
    const int lane = tid & 63;
    const int r = lane & 15;
    const int g = lane >> 4;

    __shared__ __align__(16) short k_lds[KL * C_];     // 16KB, XOR-swizzled rows
    __shared__ __align__(16) float s_lds[2 * H_ * 512];// 32KB, per-sub 32B-chunk swizzle

    const float bl2v = bl2[0];

    // persistent Q A-frags (Q pre-scaled by 1/sqrt(d) at projection)
    const bfx8 qa0 = *(const bfx8*)(Qb + ((size_t)(b * N_ + n0 + r) * C_ + h * D_ + g * 8));
    const bfx8 qa1 = *(const bfx8*)(Qb + ((size_t)(b * N_ + n0 + 16 + r) * C_ + h * D_ + g * 8));

    const int krow = tid >> 5;
    const int kcolb = (tid & 31) * 16;
    const char* Kbb = (const char*)(Kb + (size_t)b * L_ * C_);

    {   // prologue: stage K tile 0
        sh8 k0v = *(const sh8*)(Kbb + (size_t)(l0base + krow) * 512 + kcolb);
        sh8 k1v = *(const sh8*)(Kbb + (size_t)(l0base + 16 + krow) * 512 + kcolb);
        *(sh8*)((char*)k_lds + ((krow * 512 + kcolb) ^ ((krow & 7) << 4))) = k0v;
        *(sh8*)((char*)k_lds + (((krow + 16) * 512 + kcolb) ^ (((krow + 16) & 7) << 4))) = k1v;
    }

    // V pointers + prologue prefetch (one iter ahead in regs)
    const bf16* Vb0 = Vt + (size_t)((b * H_ + h) * D_ + r) * L_ + g * 8;
    const bf16* Vb1 = Vt + (size_t)((b * H_ + h) * D_ + 16 + r) * L_ + g * 8;
    bfx8 vc0 = *(const bfx8*)(Vb0 + l0base);
    bfx8 vc1 = *(const bfx8*)(Vb1 + l0base);

    float m0r = -INFINITY, s0r = 0.f, m1r = -INFINITY, s1r = 0.f;
    fx4 accA0 = {0.f,0.f,0.f,0.f}, accA1 = {0.f,0.f,0.f,0.f};
    fx4 accB0 = {0.f,0.f,0.f,0.f}, accB1 = {0.f,0.f,0.f,0.f};

    const int mn = tid >> 5;    // mask-MLP coords
    const int ml = tid & 31;
    const int moff = mn * 32 + ((((ml >> 3) ^ (mn >> 2)) & 3) << 3) + (ml & 7);
    const int abase = h * 512 + r * 32 + ((g ^ ((r >> 2) & 3)) << 3);

    for (int it = 0; it < NIT; ++it) {
        const int l0 = l0base + it * KL;
        __syncthreads();   // (1) k_lds ready; prev s_lds reads done

        // ---- S = Q K^T (kb frags shared across both sub-tiles) ----
        fx4 sA0, sA1, sB0, sB1;
        {
            const int byte0 = (r * 512 + h * 64 + g * 16) ^ ((r & 7) << 4);
            const int byte1 = ((r + 16) * 512 + h * 64 + g * 16) ^ (((r + 16) & 7) << 4);
            const bfx8 kb0 = __builtin_bit_cast(bfx8, *(const sh8*)((char*)k_lds + byte0));
            const bfx8 kb1 = __builtin_bit_cast(bfx8, *(const sh8*)((char*)k_lds + byte1));
            const fx4 z = {0.f, 0.f, 0.f, 0.f};
            sA0 = __builtin_amdgcn_mfma_f32_16x16x32_bf16(qa0, kb0, z, 0, 0, 0);
            sA1 = __builtin_amdgcn_mfma_f32_16x16x32_bf16(qa0, kb1, z, 0, 0, 0);
            sB0 = __builtin_amdgcn_mfma_f32_16x16x32_bf16(qa1, kb0, z, 0, 0, 0);
            sB1 = __builtin_amdgcn_mfma_f32_16x16x32_bf16(qa1, kb1, z, 0, 0, 0);
        }
        // publish S (D-layout rows n=4g+reg, cols r / r+16), 32B-chunk swizzle
        #pragma unroll
        for (int reg = 0; reg < 4; ++reg) {
            const int base = h * 512 + (4 * g + reg) * 32 + (r & 7);
            const int p0 = (((r >> 3)    ) ^ g) << 3;
            const int p1 = (((r >> 3) + 2) ^ g) << 3;
            s_lds[base + p0]        = sA0[reg];
            s_lds[base + p1]        = sA1[reg];
            s_lds[4096 + base + p0] = sB0[reg];
            s_lds[4096 + base + p1] = sB1[reg];
        }
        __syncthreads();   // (2) s_lds ready; k_lds consumed

        // ---- issue next K + V global loads (consumed next iter) ----
        sh8 nk0, nk1;
        bfx8 nv0, nv1;
        const bool have_next = (it + 1 < NIT);
        if (have_next) {
            nk0 = *(const sh8*)(Kbb + (size_t)(l0 + KL + krow) * 512 + kcolb);
            nk1 = *(const sh8*)(Kbb + (size_t)(l0 + KL + 16 + krow) * 512 + kcolb);
            nv0 = *(const bfx8*)(Vb0 + l0 + KL);
            nv1 = *(const bfx8*)(Vb1 + l0 + KL);
        }

        // ---- mask MLP: 2 positions (sub0, sub1) per thread ----
        {
            float sv0[8], sv1[8];
            #pragma unroll
            for (int hh = 0; hh < 8; ++hh) {
                sv0[hh] = s_lds[hh * 512 + moff];
                sv1[hh] = s_lds[4096 + hh * 512 + moff];
            }
            float mk0, mk1;
            mask_mlp2(sv0, sv1, Wl1, bl1, Wl2, bl2v, &mk0, &mk1);
            maskout[(size_t)(b * N_ + n0 + mn) * L_ + l0 + ml]      = mk0;
            maskout[(size_t)(b * N_ + n0 + 16 + mn) * L_ + l0 + ml] = mk1;
        }

        // ---- A-layout S readback: row r, l = 8g..8g+7 (both subs) ----
        const fx4 a00 = *(const fx4*)&s_lds[abase];
        const fx4 a01 = *(const fx4*)&s_lds[abase + 4];
        const fx4 a10 = *(const fx4*)&s_lds[4096 + abase];
        const fx4 a11 = *(const fx4*)&s_lds[4096 + abase + 4];

        // ---- online softmax sub0 (defer-max THR=8) ----
        bfx8 pa0, pa1;
        float ps0, ps1;
        {
            float tmax = fmaxf(fmaxf(fmaxf(a00[0], a00[1]), fmaxf(a00[2], a00[3])),
                               fmaxf(fmaxf(a01[0], a01[1]), fmaxf(a01[2], a01[3])));
            tmax = fmaxf(tmax, __shfl_xor(tmax, 16, 64));
            tmax = fmaxf(tmax, __shfl_xor(tmax, 32, 64));
            if (!__all(tmax <= m0r + 8.0f)) {
                const float mnew = fmaxf(m0r, tmax);
                const float corr = __expf(m0r - mnew);
                m0r = mnew; s0r *= corr;
                #pragma unroll
                for (int reg = 0; reg < 4; ++reg) {
                    const float cd = __shfl(corr, 4 * g + reg, 64);
                    accA0[reg] *= cd; accA1[reg] *= cd;
                }
            }
            const float p0 = __expf(a00[0] - m0r), p1 = __expf(a00[1] - m0r);
            const float p2 = __expf(a00[2] - m0r), p3 = __expf(a00[3] - m0r);
            const float p4 = __expf(a01[0] - m0r), p5 = __expf(a01[1] - m0r);
            const float p6 = __expf(a01[2] - m0r), p7 = __expf(a01[3] - m0r);
            pa0[0] = (bf16)p0; pa0[1] = (bf16)p1; pa0[2] = (bf16)p2; pa0[3] = (bf16)p3;
            pa0[4] = (bf16)p4; pa0[5] = (bf16)p5; pa0[6] = (bf16)p6; pa0[7] = (bf16)p7;
            ps0 = ((p0 + p1) + (p2 + p3)) + ((p4 + p5) + (p6 + p7));
        }
        // ---- online softmax sub1 ----
        {
            float tmax = fmaxf(fmaxf(fmaxf(a10[0], a10[1]), fmaxf(a10[2], a10[3])),
                               fmaxf(fmaxf(a11[0], a11[1]), fmaxf(a11[2], a11[3])));
            tmax = fmaxf(tmax, __shfl_xor(tmax, 16, 64));
            tmax = fmaxf(tmax, __shfl_xor(tmax, 32, 64));
            if (!__all(tmax <= m1r + 8.0f)) {
                const float mnew = fmaxf(m1r, tmax);
                const float corr = __expf(m1r - mnew);
                m1r = mnew; s1r *= corr;
                #pragma unroll
                for (int reg = 0; reg < 4; ++reg) {
                    const float cd = __shfl(corr, 4 * g + reg, 64);
                    accB0[reg] *= cd; accB1[reg] *= cd;
                }
            }
            const float p0 = __expf(a10[0] - m1r), p1 = __expf(a10[1] - m1r);
            const float p2 = __expf(a10[2] - m1r), p3 = __expf(a10[3] - m1r);
            const float p4 = __expf(a11[0] - m1r), p5 = __expf(a11[1] - m1r);
            const float p6 = __expf(a11[2] - m1r), p7 = __expf(a11[3] - m1r);
            pa1[0] = (bf16)p0; pa1[1] = (bf16)p1; pa1[2] = (bf16)p2; pa1[3] = (bf16)p3;
            pa1[4] = (bf16)p4; pa1[5] = (bf16)p5; pa1[6] = (bf16)p6; pa1[7] = (bf16)p7;
            ps1 = ((p0 + p1) + (p2 + p3)) + ((p4 + p5) + (p6 + p7));
        }

        // ---- PV MFMAs (V prefetched last iter) ----
        accA0 = __builtin_amdgcn_mfma_f32_16x16x32_bf16(pa0, vc0, accA0, 0, 0, 0);
        accA1 = __builtin_amdgcn_mfma_f32_16x16x32_bf16(pa0, vc1, accA1, 0, 0, 0);
        accB0 = __builtin_amdgcn_mfma_f32_16x16x32_bf16(pa1, vc0, accB0, 0, 0, 0);
        accB1 = __builtin_amdgcn_mfma_f32_16x16x32_bf16(pa1, vc1, accB1, 0, 0, 0);

        // ---- bookkeeping after MFMA issue ----
        ps0 += __shfl_xor(ps0, 16, 64);
        ps0 += __shfl_xor(ps0, 32, 64);
        s0r += ps0;
        ps1 += __shfl_xor(ps1, 16, 64);
        ps1 += __shfl_xor(ps1, 32, 64);
        s1r += ps1;

        if (have_next) {   // write next K tile; rotate V prefetch
            *(sh8*)((char*)k_lds + ((krow * 512 + kcolb) ^ ((krow & 7) << 4))) = nk0;
            *(sh8*)((char*)k_lds + (((krow + 16) * 512 + kcolb) ^ (((krow + 16) & 7) << 4))) = nk1;
            vc0 = nv0; vc1 = nv1;
        }
    }

    // ---- epilogue: split partials (both subs) ----
    const size_t pbase = (size_t)((b * H_ + h) * NSPLIT + split) * N_ + n0;
    #pragma unroll
    for (int reg = 0; reg < 4; ++reg) {
        const int n = 4 * g + reg;
        pacc[(pbase + n) * D_ + r]           = (bf16)accA0[reg];
        pacc[(pbase + n) * D_ + 16 + r]      = (bf16)accA1[reg];
        pacc[(pbase + 16 + n) * D_ + r]      = (bf16)accB0[reg];
        pacc[(pbase + 16 + n) * D_ + 16 + r] = (bf16)accB1[reg];
    }
    if (lane < 16) {
        pm[pbase + lane] = m0r;
        ps[pbase + lane] = s0r;
        pm[pbase + 16 + lane] = m1r;
        ps[pbase + 16 + lane] = s1r;
    }
}

// ---------- split-L combine ----------
__global__ __launch_bounds__(256)
void combine_kernel(const bf16* __restrict__ pacc, const float* __restrict__ pm,
                    const float* __restrict__ ps, float* __restrict__ xpre) {
    const int idx = blockIdx.x * 256 + threadIdx.x;   // 524288
    const int d = idx & 31;
    const int row = idx >> 5;
    const int n = row & (N_ - 1);
    const int bh = row >> 10;
    const int b = bh >> 3, hh = bh & 7;
    float mv[NSPLIT];
    float M = -INFINITY;
    #pragma unroll
    for (int sp = 0; sp < NSPLIT; ++sp) {
        mv[sp] = pm[(size_t)(bh * NSPLIT + sp) * N_ + n];
        M = fmaxf(M, mv[sp]);
    }
    float S = 0.f, X = 0.f;
    #pragma unroll
    for (int sp = 0; sp < NSPLIT; ++sp) {
        const float w = __expf(mv[sp] - M);
        S = fmaf(ps[(size_t)(bh * NSPLIT + sp) * N_ + n], w, S);
        X = fmaf((float)pacc[((size_t)(bh * NSPLIT + sp) * N_ + n) * D_ + d], w, X);
    }
    xpre[(size_t)(b * N_ + n) * C_ + hh * D_ + d] = X / S;
}

// ---------- launch ----------
extern "C" void kernel_launch(void* const* d_in, const int* in_sizes, int n_in,
                              void* d_out, int out_size, void* d_ws, size_t ws_size,
                              hipStream_t stream) {
    const float* query = (const float*)d_in[0];
    const float* key   = (const float*)d_in[1];
    const float* value = (const float*)d_in[2];
    const float* Wq  = (const float*)d_in[5];
    const float* Wk  = (const float*)d_in[6];
    const float* Wv  = (const float*)d_in[7];
    const float* Wp  = (const float*)d_in[8];
    const float* bp  = (const float*)d_in[9];
    const float* Wl1 = (const float*)d_in[10];
    const float* bl1 = (const float*)d_in[11];
    const float* Wl2 = (const float*)d_in[12];
    const float* bl2 = (const float*)d_in[13];

    float* x_out    = (float*)d_out;                 // [B,N,C]
    float* mask_out = x_out + (size_t)B_ * N_ * C_;  // [B,N,L,1]

    char* w = (char*)d_ws;
    bf16*  WTq  = (bf16*)(w);
    bf16*  WTk  = (bf16*)(w + (128 << 10));
    bf16*  WTv  = (bf16*)(w + (256 << 10));
    bf16*  WTp  = (bf16*)(w + (384 << 10));
    bf16*  Qb   = (bf16*)(w + (512 << 10));          // 1MB
    bf16*  Kb   = (bf16*)(w + (1536 << 10));         // 4MB
    bf16*  Vt   = (bf16*)(w + (5632 << 10));         // 4MB
    bf16*  pacc = (bf16*)(w + (9728 << 10));         // 8MB
    float* pm   = (float*)(w + (17920 << 10));       // 512KB
    float* ps   = (float*)(w + (18432 << 10));       // 512KB
    float* xpre = (float*)(w + (512 << 10));         // 2MB, aliases Qb+Kb[0:1MB] (dead post-attn)

    hipLaunchKernelGGL(wtrans_kernel, dim3(64), dim3(256), 0, stream,
                       Wq, Wk, Wv, Wp, WTq, WTk, WTv, WTp);
    hipLaunchKernelGGL(proj_qkv_kernel, dim3(1152), dim3(256), 8192, stream,
                       query, key, value, WTq, WTk, WTv, Qb, Kb, Vt);
    hipLaunchKernelGGL(attn_kernel, dim3(512), dim3(512), 0, stream,
                       Qb, Kb, Vt, Wl1, bl1, Wl2, bl2, pacc, pm, ps, mask_out);
    hipLaunchKernelGGL(combine_kernel, dim3(2048), dim3(256), 0, stream, pacc, pm, ps, xpre);
    hipLaunchKernelGGL(outproj_kernel, dim3(128), dim3(256), 8192, stream, xpre, WTp, bp, x_out);
}